// Round 9
// baseline (82.989 us; speedup 1.0000x reference)
//
#include <hip/hip_runtime.h>

// Problem constants (fixed by harness setup_inputs):
// B=2, V=5, C=32, H=256, W=320, D=CostNum=4, G=4
#define Bsz 2
#define Vn  5
#define Cn  32
#define Gg  4
#define Hh  256
#define Ww  320
#define Dd  4
#define HWp (Hh*Ww)

#define NVB ((Vn-1)*Bsz)                    // 8 (src view, batch) pairs
#define T_OFFSET 512                        // bytes; RT lives at ws[0..384)
// fp16-packed: 32 channels -> 16 uint32 (64 B) per pixel
#define T_BYTES ((size_t)NVB * HWp * (Cn/2) * sizeof(unsigned int))   // ~41.9 MB

// LDS-staged main kernel geometry
#define TPW 16                               // tile pixels wide
#define TPH 2                                // tile pixels high
#define PIXB (TPW*TPH)                       // 32 pixels / block
#define THREADS 128                          // 32 pixels x 4 groups
#define TILE_REC 256                         // max staged records (16 KB LDS)

typedef _Float16 half2v __attribute__((ext_vector_type(2)));

// v_dot2_f32_f16 via the official builtin: c += a.x*b.x + a.y*b.y (f32 accum)
__device__ __forceinline__ float dot2h(unsigned int a, half2v b, float c) {
    return __builtin_amdgcn_fdot2(__builtin_bit_cast(half2v, a), b, c, false);
}

// ---------------------------------------------------------------------------
// Setup kernel: per batch, build make_proj(P) for all views, invert ref proj,
// store rot(3x3)+trans(3) of src_proj @ inv(ref_proj) for each src view.
// ---------------------------------------------------------------------------
__global__ void setup_rt(const float* __restrict__ pm, float* __restrict__ RT) {
    int b = threadIdx.x;
    if (b >= Bsz) return;

    float P[Vn][16];
    for (int v = 0; v < Vn; ++v) {
        const float* E = pm + ((b * Vn + v) * 2 + 0) * 16;
        const float* K = pm + ((b * Vn + v) * 2 + 1) * 16;
        for (int i = 0; i < 3; ++i)
            for (int j = 0; j < 4; ++j) {
                float s = 0.f;
                for (int k = 0; k < 3; ++k) s += K[i * 4 + k] * E[k * 4 + j];
                P[v][i * 4 + j] = s;
            }
        for (int j = 0; j < 4; ++j) P[v][12 + j] = E[12 + j];
    }

    float A[4][8];
    for (int i = 0; i < 4; ++i)
        for (int j = 0; j < 4; ++j) {
            A[i][j] = P[0][i * 4 + j];
            A[i][4 + j] = (i == j) ? 1.f : 0.f;
        }
    for (int col = 0; col < 4; ++col) {
        int piv = col;
        float best = fabsf(A[col][col]);
        for (int r = col + 1; r < 4; ++r) {
            float v = fabsf(A[r][col]);
            if (v > best) { best = v; piv = r; }
        }
        if (piv != col)
            for (int j = 0; j < 8; ++j) {
                float t = A[col][j]; A[col][j] = A[piv][j]; A[piv][j] = t;
            }
        float inv = 1.f / A[col][col];
        for (int j = 0; j < 8; ++j) A[col][j] *= inv;
        for (int r = 0; r < 4; ++r)
            if (r != col) {
                float f = A[r][col];
                for (int j = 0; j < 8; ++j) A[r][j] -= f * A[col][j];
            }
    }
    float inv0[16];
    for (int i = 0; i < 4; ++i)
        for (int j = 0; j < 4; ++j) inv0[i * 4 + j] = A[i][4 + j];

    for (int i2 = 0; i2 < Vn - 1; ++i2) {
        const float* Ps = P[i2 + 1];
        float M[12];
        for (int i = 0; i < 3; ++i)
            for (int j = 0; j < 4; ++j) {
                float s = 0.f;
                for (int k = 0; k < 4; ++k) s += Ps[i * 4 + k] * inv0[k * 4 + j];
                M[i * 4 + j] = s;
            }
        float* o = RT + (b * (Vn - 1) + i2) * 12;
        o[0] = M[0];  o[1] = M[1];  o[2] = M[2];
        o[3] = M[4];  o[4] = M[5];  o[5] = M[6];
        o[6] = M[8];  o[7] = M[9];  o[8] = M[10];
        o[9] = M[3];  o[10] = M[7]; o[11] = M[11];
    }
}

// ---------------------------------------------------------------------------
// Transpose src views planar (C,HW) -> pixel-major fp16-packed T[vb][p][c/2].
// ---------------------------------------------------------------------------
__global__ __launch_bounds__(256) void transpose_src_fp16(
    const float* __restrict__ features, unsigned int* __restrict__ T)
{
    int tid = blockIdx.x * blockDim.x + threadIdx.x;
    if (tid >= NVB * HWp) return;
    int p  = tid % HWp;
    int vb = tid / HWp;

    const float* src = features + (size_t)(vb + Bsz) * Cn * HWp + p;
    float v[Cn];
    #pragma unroll
    for (int c = 0; c < Cn; ++c) v[c] = src[(size_t)c * HWp];

    uint4* dst = (uint4*)(T + ((size_t)vb * HWp + p) * (Cn / 2));
    #pragma unroll
    for (int q = 0; q < Cn / 8; ++q) {
        uint4 o;
        half2v p0 = { (_Float16)v[8*q + 0], (_Float16)v[8*q + 1] };
        half2v p1 = { (_Float16)v[8*q + 2], (_Float16)v[8*q + 3] };
        half2v p2 = { (_Float16)v[8*q + 4], (_Float16)v[8*q + 5] };
        half2v p3 = { (_Float16)v[8*q + 6], (_Float16)v[8*q + 7] };
        o.x = __builtin_bit_cast(unsigned int, p0);
        o.y = __builtin_bit_cast(unsigned int, p1);
        o.z = __builtin_bit_cast(unsigned int, p2);
        o.w = __builtin_bit_cast(unsigned int, p3);
        dst[q] = o;
    }
}

// ---------------------------------------------------------------------------
// Main kernel (LDS-staged): block = 16x2 pixels x 4 groups = 128 threads.
// Per view: compute corner coords; block-reduce footprint rectangle; if it
// fits TILE_REC records, cooperatively stage it coalesced into LDS and
// consume via ds_read_b128; else whole-block fallback to global gathers
// (uniform branch). Data path byte-identical to the R7 kernel.
// ---------------------------------------------------------------------------
__global__ __launch_bounds__(THREADS, 4) void getcost_lds(
    const float* __restrict__ inv_depth,
    const float* __restrict__ features,
    const float* __restrict__ view_weights,
    const float* __restrict__ confidence,
    const float* __restrict__ sc_interval,
    const float* __restrict__ sc_dmax,
    const float* __restrict__ sc_dmin,
    const float* __restrict__ RT,
    const unsigned int* __restrict__ T,
    float* __restrict__ out)
{
    __shared__ unsigned int tile[TILE_REC * 16];   // 16 KB
    __shared__ int red[8];

    int t = threadIdx.x;
    int g = t & 3;
    int pixloc = t >> 2;                 // 0..31
    int blk = blockIdx.x;
    const int TPR = Ww / TPW;            // 20 tiles per row
    const int TPI = TPR * (Hh / TPH);    // 2560 tiles per image
    int b  = blk / TPI;
    int tb = blk - b * TPI;
    int ty = tb / TPR;
    int tx = tb - ty * TPR;
    int w = tx * TPW + (pixloc & (TPW - 1));
    int h = ty * TPH + (pixloc >> 4);
    int p = h * Ww + w;

    float dI    = sc_interval[0];
    float dmaxv = sc_dmax[0];
    float dminv = sc_dmin[0];

    float cur  = inv_depth[b * HWp + p];
    float conf = confidence[b * HWp + p];
    float radius0 = (float)(Dd / 2) * dI;
    float radius  = 0.2f * radius0 + (1.0f - conf) * 1.8f * radius0;
    float dmin_   = cur - radius;
    float interval = 2.0f * radius / (float)(Dd - 1);
    float min_disp = 1.0f / dmaxv;
    float max_disp = 1.0f / dminv;

    float sample[Dd], depth[Dd];
    #pragma unroll
    for (int d = 0; d < Dd; ++d) {
        float s = (float)d * interval + dmin_;
        s = fminf(fmaxf(s, 0.0f), 1.0f);
        sample[d] = s;
        depth[d] = 1.0f / fmaxf(min_disp + (max_disp - min_disp) * s, 1e-6f);
    }

    // ref feature channels for this thread's group, packed to fp16 pairs
    half2v rp[4];
    {
        const float* reff = features + (size_t)b * Cn * HWp + (size_t)(g * 8) * HWp + p;
        #pragma unroll
        for (int j = 0; j < 4; ++j) {
            half2v pr = { (_Float16)reff[(size_t)(2*j)   * HWp],
                          (_Float16)reff[(size_t)(2*j+1) * HWp] };
            rp[j] = pr;
        }
    }

    float acc[Dd] = {0.f, 0.f, 0.f, 0.f};
    float vw_sum = 1e-8f;
    float xf = (float)w, yf = (float)h;

    #pragma unroll 1
    for (int i = 0; i < Vn - 1; ++i) {
        const float* rt = RT + (b * (Vn - 1) + i) * 12;
        float rx = rt[0] * xf + rt[1] * yf + rt[2];
        float ry = rt[3] * xf + rt[4] * yf + rt[5];
        float rz = rt[6] * xf + rt[7] * yf + rt[8];
        float t0 = rt[9], t1 = rt[10], t2 = rt[11];
        float wvw = view_weights[((size_t)(b * (Vn - 1) + i)) * HWp + p];
        vw_sum += wvw;
        float wv8 = wvw * 0.125f;

        // ---- phase 1: corner weights + clamped coords + local footprint --
        float cww[Dd][4];
        int xp[Dd], yp[Dd];
        int xlo = Ww - 1, xhi = 0, ylo = Hh - 1, yhi = 0;
        #pragma unroll
        for (int d = 0; d < Dd; ++d) {
            float dep = depth[d];
            float ptx = rx * dep + t0;
            float pty = ry * dep + t1;
            float ptz = rz * dep + t2;
            if (ptz == 0.0f) ptz = 1e-8f;
            float rcz = __builtin_amdgcn_rcpf(ptz);
            float px = ptx * rcz, py = pty * rcz;

            float x0 = floorf(px), y0 = floorf(py);
            float wx = px - x0,   wy = py - y0;
            float x1 = x0 + 1.0f, y1 = y0 + 1.0f;
            bool vx0 = (x0 >= 0.f) && (x0 <= (float)(Ww - 1));
            bool vx1 = (x1 >= 0.f) && (x1 <= (float)(Ww - 1));
            bool vy0 = (y0 >= 0.f) && (y0 <= (float)(Hh - 1));
            bool vy1 = (y1 >= 0.f) && (y1 <= (float)(Hh - 1));
            int ix0 = (int)fminf(fmaxf(x0, 0.f), (float)(Ww - 1));
            int ix1 = (int)fminf(fmaxf(x1, 0.f), (float)(Ww - 1));
            int iy0 = (int)fminf(fmaxf(y0, 0.f), (float)(Hh - 1));
            int iy1 = (int)fminf(fmaxf(y1, 0.f), (float)(Hh - 1));
            cww[d][0] = ((vx0 && vy0) ? (1.f - wx) * (1.f - wy) : 0.f) * wv8;
            cww[d][1] = ((vx1 && vy0) ? wx * (1.f - wy) : 0.f) * wv8;
            cww[d][2] = ((vx0 && vy1) ? (1.f - wx) * wy : 0.f) * wv8;
            cww[d][3] = ((vx1 && vy1) ? wx * wy : 0.f) * wv8;
            xp[d] = ix0 | (ix1 << 16);
            yp[d] = iy0 | (iy1 << 16);
            xlo = min(xlo, ix0); xhi = max(xhi, ix1);
            ylo = min(ylo, iy0); yhi = max(yhi, iy1);
        }

        // ---- phase 2: block footprint reduction --------------------------
        // lanes bits[1:0]=g carry identical values; reduce over bits 2..5.
        #pragma unroll
        for (int m = 4; m <= 32; m <<= 1) {
            xlo = min(xlo, __shfl_xor(xlo, m));
            xhi = max(xhi, __shfl_xor(xhi, m));
            ylo = min(ylo, __shfl_xor(ylo, m));
            yhi = max(yhi, __shfl_xor(yhi, m));
        }
        __syncthreads();   // A: prior view's tile/red reads complete
        if ((t & 63) == 0) {
            int w4 = (t >> 6) * 4;
            red[w4 + 0] = xlo; red[w4 + 1] = xhi;
            red[w4 + 2] = ylo; red[w4 + 3] = yhi;
        }
        __syncthreads();   // B
        xlo = min(red[0], red[4]); xhi = max(red[1], red[5]);
        ylo = min(red[2], red[6]); yhi = max(red[3], red[7]);
        int TW = xhi - xlo + 1;
        int area = TW * (yhi - ylo + 1);

        const unsigned int* tv = T + (size_t)(i * Bsz + b) * HWp * (Cn / 2);

        if (area <= TILE_REC) {
            // ---- phase 3a: coalesced staging ------------------------------
            int total16 = area * 4;                    // 16B chunks
            for (int c = t; c < total16; c += THREADS) {
                int rec = c >> 2, sub = c & 3;
                int rrow = rec / TW;
                int rcol = rec - rrow * TW;
                *(uint4*)&tile[(rec << 4) + (sub << 2)] =
                    *(const uint4*)(tv + (size_t)((ylo + rrow) * Ww + xlo + rcol) * (Cn / 2)
                                       + (sub << 2));
            }
            __syncthreads();   // C
            // ---- phase 4a: consume from LDS -------------------------------
            #pragma unroll
            for (int d = 0; d < Dd; ++d) {
                int ix0 = xp[d] & 0xffff, ix1 = xp[d] >> 16;
                int iy0 = yp[d] & 0xffff, iy1 = yp[d] >> 16;
                int dx  = ix1 - ix0;
                int i00 = (iy0 - ylo) * TW + (ix0 - xlo);
                int i01 = (iy1 - ylo) * TW + (ix0 - xlo);
                uint4 u0 = *(const uint4*)&tile[(i00 << 4) + (g << 2)];
                uint4 u1 = *(const uint4*)&tile[((i00 + dx) << 4) + (g << 2)];
                uint4 u2 = *(const uint4*)&tile[(i01 << 4) + (g << 2)];
                uint4 u3 = *(const uint4*)&tile[((i01 + dx) << 4) + (g << 2)];
                float s0 = dot2h(u0.x, rp[0], 0.f); s0 = dot2h(u0.y, rp[1], s0);
                s0 = dot2h(u0.z, rp[2], s0);        s0 = dot2h(u0.w, rp[3], s0);
                float s1 = dot2h(u1.x, rp[0], 0.f); s1 = dot2h(u1.y, rp[1], s1);
                s1 = dot2h(u1.z, rp[2], s1);        s1 = dot2h(u1.w, rp[3], s1);
                float s2 = dot2h(u2.x, rp[0], 0.f); s2 = dot2h(u2.y, rp[1], s2);
                s2 = dot2h(u2.z, rp[2], s2);        s2 = dot2h(u2.w, rp[3], s2);
                float s3 = dot2h(u3.x, rp[0], 0.f); s3 = dot2h(u3.y, rp[1], s3);
                s3 = dot2h(u3.z, rp[2], s3);        s3 = dot2h(u3.w, rp[3], s3);
                acc[d] += cww[d][0] * s0 + cww[d][1] * s1
                        + cww[d][2] * s2 + cww[d][3] * s3;
            }
        } else {
            __syncthreads();   // C (uniform barrier count)
            // ---- phase 3b/4b: fallback global gathers (R7 path) ------------
            const unsigned int* tvg = tv + g * 4;
            #pragma unroll
            for (int d = 0; d < Dd; ++d) {
                int ix0 = xp[d] & 0xffff, ix1 = xp[d] >> 16;
                int iy0 = yp[d] & 0xffff, iy1 = yp[d] >> 16;
                int c00 = iy0 * Ww + ix0, c10 = iy0 * Ww + ix1;
                int c01 = iy1 * Ww + ix0, c11 = iy1 * Ww + ix1;
                uint4 u0 = *(const uint4*)(tvg + (size_t)c00 * (Cn / 2));
                uint4 u1 = *(const uint4*)(tvg + (size_t)c10 * (Cn / 2));
                uint4 u2 = *(const uint4*)(tvg + (size_t)c01 * (Cn / 2));
                uint4 u3 = *(const uint4*)(tvg + (size_t)c11 * (Cn / 2));
                float s0 = dot2h(u0.x, rp[0], 0.f); s0 = dot2h(u0.y, rp[1], s0);
                s0 = dot2h(u0.z, rp[2], s0);        s0 = dot2h(u0.w, rp[3], s0);
                float s1 = dot2h(u1.x, rp[0], 0.f); s1 = dot2h(u1.y, rp[1], s1);
                s1 = dot2h(u1.z, rp[2], s1);        s1 = dot2h(u1.w, rp[3], s1);
                float s2 = dot2h(u2.x, rp[0], 0.f); s2 = dot2h(u2.y, rp[1], s2);
                s2 = dot2h(u2.z, rp[2], s2);        s2 = dot2h(u2.w, rp[3], s2);
                float s3 = dot2h(u3.x, rp[0], 0.f); s3 = dot2h(u3.y, rp[1], s3);
                s3 = dot2h(u3.z, rp[2], s3);        s3 = dot2h(u3.w, rp[3], s3);
                acc[d] += cww[d][0] * s0 + cww[d][1] * s1
                        + cww[d][2] * s2 + cww[d][3] * s3;
            }
        }
    }

    float invvw = 1.0f / vw_sum;
    size_t outbase = (size_t)b * Gg * Dd * HWp;
    #pragma unroll
    for (int d = 0; d < Dd; ++d)
        out[outbase + (size_t)(g * Dd + d) * HWp + p] = acc[d] * invvw;
    if (g == 0) {
        size_t sbase = (size_t)Bsz * Gg * Dd * HWp + (size_t)b * Dd * HWp + p;
        #pragma unroll
        for (int d = 0; d < Dd; ++d)
            out[sbase + (size_t)d * HWp] = sample[d];
    }
}

// ---------------------------------------------------------------------------
// Fallback kernel (verified R1 path) if ws is too small for the transpose.
// ---------------------------------------------------------------------------
__global__ __launch_bounds__(256) void getcost_main(
    const float* __restrict__ inv_depth,
    const float* __restrict__ features,
    const float* __restrict__ view_weights,
    const float* __restrict__ confidence,
    const float* __restrict__ sc_interval,
    const float* __restrict__ sc_dmax,
    const float* __restrict__ sc_dmin,
    const float* __restrict__ RT,
    float* __restrict__ out)
{
    int tid = blockIdx.x * blockDim.x + threadIdx.x;
    if (tid >= Bsz * Dd * HWp) return;
    int p  = tid % HWp;
    int bd = tid / HWp;
    int d  = bd % Dd;
    int b  = bd / Dd;
    int h  = p / Ww;
    int w  = p % Ww;

    float dI    = sc_interval[0];
    float dmaxv = sc_dmax[0];
    float dminv = sc_dmin[0];

    float cur  = inv_depth[b * HWp + p];
    float conf = confidence[b * HWp + p];
    float radius0 = (float)(Dd / 2) * dI;
    float radius  = 0.2f * radius0 + (1.0f - conf) * 1.8f * radius0;
    float dmin_   = cur - radius;
    float interval = 2.0f * radius / (float)(Dd - 1);
    float sample = (float)d * interval + dmin_;
    sample = fminf(fmaxf(sample, 0.0f), 1.0f);
    float min_disp = 1.0f / dmaxv;
    float max_disp = 1.0f / dminv;
    float depth = 1.0f / fmaxf(min_disp + (max_disp - min_disp) * sample, 1e-6f);

    float ref[Cn];
    const float* reff = features + (size_t)b * Cn * HWp + p;
    #pragma unroll
    for (int c = 0; c < Cn; ++c) ref[c] = reff[(size_t)c * HWp];

    float acc[Gg] = {0.f, 0.f, 0.f, 0.f};
    float vw_sum = 1e-8f;
    float xf = (float)w, yf = (float)h;

    #pragma unroll
    for (int i = 0; i < Vn - 1; ++i) {
        const float* rt = RT + (b * (Vn - 1) + i) * 12;
        float rx = rt[0] * xf + rt[1] * yf + rt[2];
        float ry = rt[3] * xf + rt[4] * yf + rt[5];
        float rz = rt[6] * xf + rt[7] * yf + rt[8];
        float wvw = view_weights[((size_t)(b * (Vn - 1) + i)) * HWp + p];
        vw_sum += wvw;

        float ptx = rx * depth + rt[9];
        float pty = ry * depth + rt[10];
        float ptz = rz * depth + rt[11];
        if (ptz == 0.0f) ptz = 1e-8f;
        float px = ptx / ptz, py = pty / ptz;

        float x0 = floorf(px), y0 = floorf(py);
        float wx = px - x0,   wy = py - y0;
        float x1 = x0 + 1.0f, y1 = y0 + 1.0f;
        bool vx0 = (x0 >= 0.f) && (x0 <= (float)(Ww - 1));
        bool vx1 = (x1 >= 0.f) && (x1 <= (float)(Ww - 1));
        bool vy0 = (y0 >= 0.f) && (y0 <= (float)(Hh - 1));
        bool vy1 = (y1 >= 0.f) && (y1 <= (float)(Hh - 1));
        int ix0 = (int)fminf(fmaxf(x0, 0.f), (float)(Ww - 1));
        int ix1 = (int)fminf(fmaxf(x1, 0.f), (float)(Ww - 1));
        int iy0 = (int)fminf(fmaxf(y0, 0.f), (float)(Hh - 1));
        int iy1 = (int)fminf(fmaxf(y1, 0.f), (float)(Hh - 1));
        float w00 = (vx0 && vy0) ? (1.f - wx) * (1.f - wy) : 0.f;
        float w10 = (vx1 && vy0) ? wx * (1.f - wy) : 0.f;
        float w01 = (vx0 && vy1) ? (1.f - wx) * wy : 0.f;
        float w11 = (vx1 && vy1) ? wx * wy : 0.f;
        int o00 = iy0 * Ww + ix0, o10 = iy0 * Ww + ix1;
        int o01 = iy1 * Ww + ix0, o11 = iy1 * Ww + ix1;

        const float* src = features + (size_t)((i + 1) * Bsz + b) * Cn * HWp;
        float wv8 = wvw * 0.125f;
        #pragma unroll
        for (int c = 0; c < Cn; ++c) {
            const float* sc = src + (size_t)c * HWp;
            float v = w00 * sc[o00] + w10 * sc[o10] + w01 * sc[o01] + w11 * sc[o11];
            acc[c >> 3] += v * ref[c] * wv8;
        }
    }

    float invvw = 1.0f / vw_sum;
    size_t outbase = (size_t)b * Gg * Dd * HWp;
    #pragma unroll
    for (int g = 0; g < Gg; ++g)
        out[outbase + (size_t)(g * Dd + d) * HWp + p] = acc[g] * invvw;
    out[(size_t)Bsz * Gg * Dd * HWp + (size_t)(b * Dd + d) * HWp + p] = sample;
}

extern "C" void kernel_launch(void* const* d_in, const int* in_sizes, int n_in,
                              void* d_out, int out_size, void* d_ws, size_t ws_size,
                              hipStream_t stream) {
    const float* inv_depth = (const float*)d_in[0];
    const float* features  = (const float*)d_in[1];
    const float* pm        = (const float*)d_in[2];
    const float* vw        = (const float*)d_in[3];
    const float* conf      = (const float*)d_in[4];
    const float* dI        = (const float*)d_in[5];
    const float* dmax      = (const float*)d_in[6];
    const float* dmin      = (const float*)d_in[7];
    float* RT = (float*)d_ws;

    hipLaunchKernelGGL(setup_rt, dim3(1), dim3(64), 0, stream, pm, RT);

    bool has_ws = (ws_size >= T_OFFSET + T_BYTES);

    if (has_ws) {
        unsigned int* T = (unsigned int*)((char*)d_ws + T_OFFSET);
        int ttot = NVB * HWp;
        hipLaunchKernelGGL(transpose_src_fp16, dim3((ttot + 255) / 256), dim3(256), 0,
                           stream, features, T);
        int nblk = Bsz * HWp / PIXB;   // 5120 blocks of 128 threads (exact)
        hipLaunchKernelGGL(getcost_lds, dim3(nblk), dim3(THREADS), 0, stream,
                           inv_depth, features, vw, conf, dI, dmax, dmin, RT, T,
                           (float*)d_out);
    } else {
        int total = Bsz * Dd * HWp;
        hipLaunchKernelGGL(getcost_main, dim3((total + 255) / 256), dim3(256), 0, stream,
                           inv_depth, features, vw, conf, dI, dmax, dmin, RT,
                           (float*)d_out);
    }
}

// Round 10
// 65.668 us; speedup vs baseline: 1.2638x; 1.2638x over previous
//
#include <hip/hip_runtime.h>

// Problem constants (fixed by harness setup_inputs):
// B=2, V=5, C=32, H=256, W=320, D=CostNum=4, G=4
#define Bsz 2
#define Vn  5
#define Cn  32
#define Gg  4
#define Hh  256
#define Ww  320
#define Dd  4
#define HWp (Hh*Ww)

#define NVB ((Vn-1)*Bsz)                    // 8 (src view, batch) pairs
#define T_OFFSET 512                        // bytes; RT lives at ws[0..384)
// fp16-packed: 32 channels -> 16 uint32 (64 B) per pixel
#define T_BYTES ((size_t)NVB * HWp * (Cn/2) * sizeof(unsigned int))   // ~41.9 MB

typedef _Float16 half2v __attribute__((ext_vector_type(2)));

// v_dot2_f32_f16 via the official builtin: c += a.x*b.x + a.y*b.y (f32 accum)
__device__ __forceinline__ float dot2h(unsigned int a, half2v b, float c) {
    return __builtin_amdgcn_fdot2(__builtin_bit_cast(half2v, a), b, c, false);
}

// ---------------------------------------------------------------------------
// Setup kernel: per batch, build make_proj(P) for all views, invert ref proj,
// store rot(3x3)+trans(3) of src_proj @ inv(ref_proj) for each src view.
// ---------------------------------------------------------------------------
__global__ void setup_rt(const float* __restrict__ pm, float* __restrict__ RT) {
    int b = threadIdx.x;
    if (b >= Bsz) return;

    float P[Vn][16];
    for (int v = 0; v < Vn; ++v) {
        const float* E = pm + ((b * Vn + v) * 2 + 0) * 16;
        const float* K = pm + ((b * Vn + v) * 2 + 1) * 16;
        for (int i = 0; i < 3; ++i)
            for (int j = 0; j < 4; ++j) {
                float s = 0.f;
                for (int k = 0; k < 3; ++k) s += K[i * 4 + k] * E[k * 4 + j];
                P[v][i * 4 + j] = s;
            }
        for (int j = 0; j < 4; ++j) P[v][12 + j] = E[12 + j];
    }

    float A[4][8];
    for (int i = 0; i < 4; ++i)
        for (int j = 0; j < 4; ++j) {
            A[i][j] = P[0][i * 4 + j];
            A[i][4 + j] = (i == j) ? 1.f : 0.f;
        }
    for (int col = 0; col < 4; ++col) {
        int piv = col;
        float best = fabsf(A[col][col]);
        for (int r = col + 1; r < 4; ++r) {
            float v = fabsf(A[r][col]);
            if (v > best) { best = v; piv = r; }
        }
        if (piv != col)
            for (int j = 0; j < 8; ++j) {
                float t = A[col][j]; A[col][j] = A[piv][j]; A[piv][j] = t;
            }
        float inv = 1.f / A[col][col];
        for (int j = 0; j < 8; ++j) A[col][j] *= inv;
        for (int r = 0; r < 4; ++r)
            if (r != col) {
                float f = A[r][col];
                for (int j = 0; j < 8; ++j) A[r][j] -= f * A[col][j];
            }
    }
    float inv0[16];
    for (int i = 0; i < 4; ++i)
        for (int j = 0; j < 4; ++j) inv0[i * 4 + j] = A[i][4 + j];

    for (int i2 = 0; i2 < Vn - 1; ++i2) {
        const float* Ps = P[i2 + 1];
        float M[12];
        for (int i = 0; i < 3; ++i)
            for (int j = 0; j < 4; ++j) {
                float s = 0.f;
                for (int k = 0; k < 4; ++k) s += Ps[i * 4 + k] * inv0[k * 4 + j];
                M[i * 4 + j] = s;
            }
        float* o = RT + (b * (Vn - 1) + i2) * 12;
        o[0] = M[0];  o[1] = M[1];  o[2] = M[2];
        o[3] = M[4];  o[4] = M[5];  o[5] = M[6];
        o[6] = M[8];  o[7] = M[9];  o[8] = M[10];
        o[9] = M[3];  o[10] = M[7]; o[11] = M[11];
    }
}

// ---------------------------------------------------------------------------
// Transpose src views planar (C,HW) -> pixel-major fp16-packed T[vb][p][c/2].
// ---------------------------------------------------------------------------
__global__ __launch_bounds__(256) void transpose_src_fp16(
    const float* __restrict__ features, unsigned int* __restrict__ T)
{
    int tid = blockIdx.x * blockDim.x + threadIdx.x;
    if (tid >= NVB * HWp) return;
    int p  = tid % HWp;
    int vb = tid / HWp;

    const float* src = features + (size_t)(vb + Bsz) * Cn * HWp + p;
    float v[Cn];
    #pragma unroll
    for (int c = 0; c < Cn; ++c) v[c] = src[(size_t)c * HWp];

    uint4* dst = (uint4*)(T + ((size_t)vb * HWp + p) * (Cn / 2));
    #pragma unroll
    for (int q = 0; q < Cn / 8; ++q) {
        uint4 o;
        half2v p0 = { (_Float16)v[8*q + 0], (_Float16)v[8*q + 1] };
        half2v p1 = { (_Float16)v[8*q + 2], (_Float16)v[8*q + 3] };
        half2v p2 = { (_Float16)v[8*q + 4], (_Float16)v[8*q + 5] };
        half2v p3 = { (_Float16)v[8*q + 6], (_Float16)v[8*q + 7] };
        o.x = __builtin_bit_cast(unsigned int, p0);
        o.y = __builtin_bit_cast(unsigned int, p1);
        o.z = __builtin_bit_cast(unsigned int, p2);
        o.w = __builtin_bit_cast(unsigned int, p3);
        dst[q] = o;
    }
}

// ---------------------------------------------------------------------------
// Main kernel (group-split + fdot2 + XCD-aware block swizzle): one thread per
// (b,pixel,group). Consecutive LOGICAL blocks share warped footprints; the
// swizzle maps a contiguous stripe of logical blocks to each XCD so the
// per-XCD L2 working set of T drops from ~42MB to ~5MB (fits 4MB L2 + halo)
// -> gathers served from L2 instead of Infinity Cache.
// ---------------------------------------------------------------------------
__global__ __launch_bounds__(256, 2) void getcost_fast(
    const float* __restrict__ inv_depth,
    const float* __restrict__ features,
    const float* __restrict__ view_weights,
    const float* __restrict__ confidence,
    const float* __restrict__ sc_interval,
    const float* __restrict__ sc_dmax,
    const float* __restrict__ sc_dmin,
    const float* __restrict__ RT,
    const unsigned int* __restrict__ T,
    float* __restrict__ out)
{
    // XCD-aware bijective swizzle: HW dispatches consecutive blockIdx
    // round-robin over 8 XCDs; relabel so XCD k gets logical blocks
    // [k*cpx, (k+1)*cpx) -- a contiguous image stripe. gridDim.x % 8 == 0.
    int cpx  = (int)gridDim.x >> 3;                      // 640
    int lbid = ((int)blockIdx.x & 7) * cpx + ((int)blockIdx.x >> 3);
    int tid  = lbid * 256 + (int)threadIdx.x;            // < Bsz*HWp*Gg (exact)

    int g    = tid & 3;
    int rest = tid >> 2;          // b*HWp + p
    int p = rest % HWp;
    int b = rest / HWp;
    int h = p / Ww;
    int w = p % Ww;

    float dI    = sc_interval[0];
    float dmaxv = sc_dmax[0];
    float dminv = sc_dmin[0];

    float cur  = inv_depth[b * HWp + p];
    float conf = confidence[b * HWp + p];
    float radius0 = (float)(Dd / 2) * dI;
    float radius  = 0.2f * radius0 + (1.0f - conf) * 1.8f * radius0;
    float dmin_   = cur - radius;
    float interval = 2.0f * radius / (float)(Dd - 1);
    float min_disp = 1.0f / dmaxv;
    float max_disp = 1.0f / dminv;

    float sample[Dd], depth[Dd];
    #pragma unroll
    for (int d = 0; d < Dd; ++d) {
        float s = (float)d * interval + dmin_;
        s = fminf(fmaxf(s, 0.0f), 1.0f);
        sample[d] = s;
        depth[d] = 1.0f / fmaxf(min_disp + (max_disp - min_disp) * s, 1e-6f);
    }

    // ref feature channels for this thread's group, packed to fp16 pairs
    half2v rp[4];
    {
        const float* reff = features + (size_t)b * Cn * HWp + (size_t)(g * 8) * HWp + p;
        #pragma unroll
        for (int j = 0; j < 4; ++j) {
            half2v pr = { (_Float16)reff[(size_t)(2*j)   * HWp],
                          (_Float16)reff[(size_t)(2*j+1) * HWp] };
            rp[j] = pr;
        }
    }

    float acc[Dd] = {0.f, 0.f, 0.f, 0.f};
    float vw_sum = 1e-8f;
    float xf = (float)w, yf = (float)h;

    #pragma unroll
    for (int i = 0; i < Vn - 1; ++i) {
        const float* rt = RT + (b * (Vn - 1) + i) * 12;
        float rx = rt[0] * xf + rt[1] * yf + rt[2];
        float ry = rt[3] * xf + rt[4] * yf + rt[5];
        float rz = rt[6] * xf + rt[7] * yf + rt[8];
        float t0 = rt[9], t1 = rt[10], t2 = rt[11];
        float wvw = view_weights[((size_t)(b * (Vn - 1) + i)) * HWp + p];
        vw_sum += wvw;
        float wv8 = wvw * 0.125f;

        // base for this view+group: record stride 16 uints, chunk g at +4g
        const unsigned int* tvg = T + (size_t)(i * Bsz + b) * HWp * (Cn / 2) + g * 4;

        // ---- phase 1: all 16 corner weights + offsets -------------------
        float cww[Dd][4];
        int   cox[Dd][4];
        #pragma unroll
        for (int d = 0; d < Dd; ++d) {
            float dep = depth[d];
            float ptx = rx * dep + t0;
            float pty = ry * dep + t1;
            float ptz = rz * dep + t2;
            if (ptz == 0.0f) ptz = 1e-8f;
            float rcz = __builtin_amdgcn_rcpf(ptz);
            float px = ptx * rcz, py = pty * rcz;

            float x0 = floorf(px), y0 = floorf(py);
            float wx = px - x0,   wy = py - y0;
            float x1 = x0 + 1.0f, y1 = y0 + 1.0f;
            bool vx0 = (x0 >= 0.f) && (x0 <= (float)(Ww - 1));
            bool vx1 = (x1 >= 0.f) && (x1 <= (float)(Ww - 1));
            bool vy0 = (y0 >= 0.f) && (y0 <= (float)(Hh - 1));
            bool vy1 = (y1 >= 0.f) && (y1 <= (float)(Hh - 1));
            int ix0 = (int)fminf(fmaxf(x0, 0.f), (float)(Ww - 1));
            int ix1 = (int)fminf(fmaxf(x1, 0.f), (float)(Ww - 1));
            int iy0 = (int)fminf(fmaxf(y0, 0.f), (float)(Hh - 1));
            int iy1 = (int)fminf(fmaxf(y1, 0.f), (float)(Hh - 1));
            cww[d][0] = ((vx0 && vy0) ? (1.f - wx) * (1.f - wy) : 0.f) * wv8;
            cww[d][1] = ((vx1 && vy0) ? wx * (1.f - wy) : 0.f) * wv8;
            cww[d][2] = ((vx0 && vy1) ? (1.f - wx) * wy : 0.f) * wv8;
            cww[d][3] = ((vx1 && vy1) ? wx * wy : 0.f) * wv8;
            cox[d][0] = iy0 * Ww + ix0; cox[d][1] = iy0 * Ww + ix1;
            cox[d][2] = iy1 * Ww + ix0; cox[d][3] = iy1 * Ww + ix1;
        }

        // ---- phase 2: issue all 16 independent gathers ------------------
        uint4 uu[Dd][4];
        #pragma unroll
        for (int d = 0; d < Dd; ++d)
            #pragma unroll
            for (int k = 0; k < 4; ++k)
                uu[d][k] = *(const uint4*)(tvg + (size_t)cox[d][k] * (Cn / 2));

        // ---- phase 3: accumulate ---------------------------------------
        #pragma unroll
        for (int d = 0; d < Dd; ++d) {
            #pragma unroll
            for (int k = 0; k < 4; ++k) {
                float t = dot2h(uu[d][k].x, rp[0], 0.0f);
                t = dot2h(uu[d][k].y, rp[1], t);
                t = dot2h(uu[d][k].z, rp[2], t);
                t = dot2h(uu[d][k].w, rp[3], t);
                acc[d] += cww[d][k] * t;
            }
        }
    }

    float invvw = 1.0f / vw_sum;
    size_t outbase = (size_t)b * Gg * Dd * HWp;
    #pragma unroll
    for (int d = 0; d < Dd; ++d)
        out[outbase + (size_t)(g * Dd + d) * HWp + p] = acc[d] * invvw;
    if (g == 0) {
        size_t sbase = (size_t)Bsz * Gg * Dd * HWp + (size_t)b * Dd * HWp + p;
        #pragma unroll
        for (int d = 0; d < Dd; ++d)
            out[sbase + (size_t)d * HWp] = sample[d];
    }
}

// ---------------------------------------------------------------------------
// Fallback kernel (verified R1 path) if ws is too small for the transpose.
// ---------------------------------------------------------------------------
__global__ __launch_bounds__(256) void getcost_main(
    const float* __restrict__ inv_depth,
    const float* __restrict__ features,
    const float* __restrict__ view_weights,
    const float* __restrict__ confidence,
    const float* __restrict__ sc_interval,
    const float* __restrict__ sc_dmax,
    const float* __restrict__ sc_dmin,
    const float* __restrict__ RT,
    float* __restrict__ out)
{
    int tid = blockIdx.x * blockDim.x + threadIdx.x;
    if (tid >= Bsz * Dd * HWp) return;
    int p  = tid % HWp;
    int bd = tid / HWp;
    int d  = bd % Dd;
    int b  = bd / Dd;
    int h  = p / Ww;
    int w  = p % Ww;

    float dI    = sc_interval[0];
    float dmaxv = sc_dmax[0];
    float dminv = sc_dmin[0];

    float cur  = inv_depth[b * HWp + p];
    float conf = confidence[b * HWp + p];
    float radius0 = (float)(Dd / 2) * dI;
    float radius  = 0.2f * radius0 + (1.0f - conf) * 1.8f * radius0;
    float dmin_   = cur - radius;
    float interval = 2.0f * radius / (float)(Dd - 1);
    float sample = (float)d * interval + dmin_;
    sample = fminf(fmaxf(sample, 0.0f), 1.0f);
    float min_disp = 1.0f / dmaxv;
    float max_disp = 1.0f / dminv;
    float depth = 1.0f / fmaxf(min_disp + (max_disp - min_disp) * sample, 1e-6f);

    float ref[Cn];
    const float* reff = features + (size_t)b * Cn * HWp + p;
    #pragma unroll
    for (int c = 0; c < Cn; ++c) ref[c] = reff[(size_t)c * HWp];

    float acc[Gg] = {0.f, 0.f, 0.f, 0.f};
    float vw_sum = 1e-8f;
    float xf = (float)w, yf = (float)h;

    #pragma unroll
    for (int i = 0; i < Vn - 1; ++i) {
        const float* rt = RT + (b * (Vn - 1) + i) * 12;
        float rx = rt[0] * xf + rt[1] * yf + rt[2];
        float ry = rt[3] * xf + rt[4] * yf + rt[5];
        float rz = rt[6] * xf + rt[7] * yf + rt[8];
        float wvw = view_weights[((size_t)(b * (Vn - 1) + i)) * HWp + p];
        vw_sum += wvw;

        float ptx = rx * depth + rt[9];
        float pty = ry * depth + rt[10];
        float ptz = rz * depth + rt[11];
        if (ptz == 0.0f) ptz = 1e-8f;
        float px = ptx / ptz, py = pty / ptz;

        float x0 = floorf(px), y0 = floorf(py);
        float wx = px - x0,   wy = py - y0;
        float x1 = x0 + 1.0f, y1 = y0 + 1.0f;
        bool vx0 = (x0 >= 0.f) && (x0 <= (float)(Ww - 1));
        bool vx1 = (x1 >= 0.f) && (x1 <= (float)(Ww - 1));
        bool vy0 = (y0 >= 0.f) && (y0 <= (float)(Hh - 1));
        bool vy1 = (y1 >= 0.f) && (y1 <= (float)(Hh - 1));
        int ix0 = (int)fminf(fmaxf(x0, 0.f), (float)(Ww - 1));
        int ix1 = (int)fminf(fmaxf(x1, 0.f), (float)(Ww - 1));
        int iy0 = (int)fminf(fmaxf(y0, 0.f), (float)(Hh - 1));
        int iy1 = (int)fminf(fmaxf(y1, 0.f), (float)(Hh - 1));
        float w00 = (vx0 && vy0) ? (1.f - wx) * (1.f - wy) : 0.f;
        float w10 = (vx1 && vy0) ? wx * (1.f - wy) : 0.f;
        float w01 = (vx0 && vy1) ? (1.f - wx) * wy : 0.f;
        float w11 = (vx1 && vy1) ? wx * wy : 0.f;
        int o00 = iy0 * Ww + ix0, o10 = iy0 * Ww + ix1;
        int o01 = iy1 * Ww + ix0, o11 = iy1 * Ww + ix1;

        const float* src = features + (size_t)((i + 1) * Bsz + b) * Cn * HWp;
        float wv8 = wvw * 0.125f;
        #pragma unroll
        for (int c = 0; c < Cn; ++c) {
            const float* sc = src + (size_t)c * HWp;
            float v = w00 * sc[o00] + w10 * sc[o10] + w01 * sc[o01] + w11 * sc[o11];
            acc[c >> 3] += v * ref[c] * wv8;
        }
    }

    float invvw = 1.0f / vw_sum;
    size_t outbase = (size_t)b * Gg * Dd * HWp;
    #pragma unroll
    for (int g = 0; g < Gg; ++g)
        out[outbase + (size_t)(g * Dd + d) * HWp + p] = acc[g] * invvw;
    out[(size_t)Bsz * Gg * Dd * HWp + (size_t)(b * Dd + d) * HWp + p] = sample;
}

extern "C" void kernel_launch(void* const* d_in, const int* in_sizes, int n_in,
                              void* d_out, int out_size, void* d_ws, size_t ws_size,
                              hipStream_t stream) {
    const float* inv_depth = (const float*)d_in[0];
    const float* features  = (const float*)d_in[1];
    const float* pm        = (const float*)d_in[2];
    const float* vw        = (const float*)d_in[3];
    const float* conf      = (const float*)d_in[4];
    const float* dI        = (const float*)d_in[5];
    const float* dmax      = (const float*)d_in[6];
    const float* dmin      = (const float*)d_in[7];
    float* RT = (float*)d_ws;

    hipLaunchKernelGGL(setup_rt, dim3(1), dim3(64), 0, stream, pm, RT);

    bool has_ws = (ws_size >= T_OFFSET + T_BYTES);

    if (has_ws) {
        unsigned int* T = (unsigned int*)((char*)d_ws + T_OFFSET);
        int ttot = NVB * HWp;
        hipLaunchKernelGGL(transpose_src_fp16, dim3((ttot + 255) / 256), dim3(256), 0,
                           stream, features, T);
        int total = Bsz * HWp * Gg;   // 1,310,720 -> 5120 blocks (exact, %8==0)
        hipLaunchKernelGGL(getcost_fast, dim3(total / 256), dim3(256), 0, stream,
                           inv_depth, features, vw, conf, dI, dmax, dmin, RT, T,
                           (float*)d_out);
    } else {
        int total = Bsz * Dd * HWp;
        hipLaunchKernelGGL(getcost_main, dim3((total + 255) / 256), dim3(256), 0, stream,
                           inv_depth, features, vw, conf, dI, dmax, dmin, RT,
                           (float*)d_out);
    }
}